// Round 1
// baseline (603.438 us; speedup 1.0000x reference)
//
#include <hip/hip_runtime.h>
#include <stdint.h>

#define T_TOK 2048
#define DD 1024
#define EE 8
#define FF 2048
#define SLOTPAD 4224   // T*K + 128 pad rows

typedef __attribute__((ext_vector_type(8))) __bf16 bf16x8;
typedef __attribute__((ext_vector_type(4))) float floatx4;

__device__ __forceinline__ unsigned short f2bf(float f){
  union { float f; unsigned u; } v; v.f = f;
  unsigned r = v.u + 0x7fffu + ((v.u >> 16) & 1u);
  return (unsigned short)(r >> 16);
}

// ---------------- fp32 -> bf16 weight convert ----------------
__global__ __launch_bounds__(256) void k_cvt_bf16(const float* __restrict__ in,
    unsigned short* __restrict__ out, int n4)
{
  int i = blockIdx.x * 256 + threadIdx.x;
  const int stride = gridDim.x * 256;
  for (; i < n4; i += stride){
    const float4 v = ((const float4*)in)[i];
    ushort4 o; o.x = f2bf(v.x); o.y = f2bf(v.y); o.z = f2bf(v.z); o.w = f2bf(v.w);
    ((ushort4*)out)[i] = o;
  }
}

// ---------------- RMSNorm + router (one block per token) ----------------
__global__ __launch_bounds__(256) void k_rms_router(
    const float* __restrict__ x, const float* __restrict__ gw,
    const float* __restrict__ nw,
    unsigned short* __restrict__ xn,
    int* __restrict__ topk_id, float* __restrict__ topk_w,
    int* __restrict__ counts, int* __restrict__ cnt1,
    float* __restrict__ sumprob)
{
  const int t = blockIdx.x, tid = threadIdx.x;
  const float4 xv = ((const float4*)(x + (size_t)t * DD))[tid];
  float ss = xv.x*xv.x + xv.y*xv.y + xv.z*xv.z + xv.w*xv.w;
  #pragma unroll
  for (int o = 32; o > 0; o >>= 1) ss += __shfl_down(ss, o);
  __shared__ float s_ss[4];
  __shared__ float s_p[4][8];
  if ((tid & 63) == 0) s_ss[tid >> 6] = ss;
  __syncthreads();
  const float tot = s_ss[0] + s_ss[1] + s_ss[2] + s_ss[3];
  const float inv = rsqrtf(tot * (1.0f / DD) + 1.1920929e-7f);
  const float4 nv = ((const float4*)nw)[tid];
  float4 xnv;
  xnv.x = xv.x*inv*nv.x; xnv.y = xv.y*inv*nv.y;
  xnv.z = xv.z*inv*nv.z; xnv.w = xv.w*inv*nv.w;
  ushort4 bv; bv.x = f2bf(xnv.x); bv.y = f2bf(xnv.y); bv.z = f2bf(xnv.z); bv.w = f2bf(xnv.w);
  ((ushort4*)(xn + (size_t)t * DD))[tid] = bv;
  float p[8];
  #pragma unroll
  for (int e = 0; e < 8; e++){
    const float4 g = ((const float4*)(gw + e * DD))[tid];
    p[e] = xnv.x*g.x + xnv.y*g.y + xnv.z*g.z + xnv.w*g.w;
  }
  #pragma unroll
  for (int e = 0; e < 8; e++){
    #pragma unroll
    for (int o = 32; o > 0; o >>= 1) p[e] += __shfl_down(p[e], o);
  }
  if ((tid & 63) == 0){
    #pragma unroll
    for (int e = 0; e < 8; e++) s_p[tid >> 6][e] = p[e];
  }
  __syncthreads();
  if (tid == 0){
    float lg[8], pr[8];
    #pragma unroll
    for (int e = 0; e < 8; e++) lg[e] = s_p[0][e] + s_p[1][e] + s_p[2][e] + s_p[3][e];
    float mx = lg[0];
    for (int e = 1; e < 8; e++) mx = fmaxf(mx, lg[e]);
    float sum = 0.f;
    for (int e = 0; e < 8; e++){ pr[e] = __expf(lg[e] - mx); sum += pr[e]; }
    const float is = 1.f / sum;
    for (int e = 0; e < 8; e++) pr[e] *= is;
    int e1 = 0;
    for (int e = 1; e < 8; e++) if (pr[e] > pr[e1]) e1 = e;       // first max (tie: lower idx)
    int e2 = (e1 == 0) ? 1 : 0;
    for (int e = 0; e < 8; e++) if (e != e1 && e != e2 && pr[e] > pr[e2]) e2 = e;
    const float wsum = fmaxf(pr[e1] + pr[e2], 1e-6f);
    topk_id[2*t] = e1; topk_id[2*t+1] = e2;
    topk_w[2*t] = pr[e1] / wsum; topk_w[2*t+1] = pr[e2] / wsum;
    #pragma unroll
    for (int e = 0; e < 8; e++) atomicAdd(&sumprob[e], pr[e]);
    atomicAdd(&cnt1[e1], 1);
    atomicAdd(&counts[e1], 1);
    atomicAdd(&counts[e2], 1);
  }
}

// ---------------- prefix bases + lb loss ----------------
__global__ void k_prep(const int* __restrict__ counts, int* __restrict__ bases,
                       const int* __restrict__ cnt1, const float* __restrict__ sumprob,
                       float* __restrict__ lb_out)
{
  if (threadIdx.x == 0 && blockIdx.x == 0){
    int b = 0;
    for (int e = 0; e < 8; e++){ bases[e] = b; b += counts[e]; }
    float lb = 0.f;
    for (int e = 0; e < 8; e++)
      lb += ((float)cnt1[e] * (1.f / T_TOK)) * (sumprob[e] * (1.f / T_TOK));
    lb_out[0] = 8.f * lb;
  }
}

// ---------------- slot assignment + row gather ----------------
__global__ __launch_bounds__(256) void k_assign(
    const int* __restrict__ topk_id, const float* __restrict__ topk_w,
    const int* __restrict__ bases, int* __restrict__ ctr,
    int* __restrict__ slots_of, float* __restrict__ slot_w,
    const unsigned short* __restrict__ xn, unsigned short* __restrict__ xg)
{
  const int t = blockIdx.x, tid = threadIdx.x;
  __shared__ int s_slot[2];
  if (tid < 2){
    const int e = topk_id[2*t + tid];
    const int pos = atomicAdd(&ctr[e], 1);
    const int slot = bases[e] + pos;
    s_slot[tid] = slot;
    slot_w[slot] = topk_w[2*t + tid];
    slots_of[2*t + tid] = slot;
  }
  __syncthreads();
  const uint4* src = (const uint4*)(xn + (size_t)t * DD);
  const int k = tid >> 7, c = tid & 127;          // 128 x 16B per row, 2 rows per block
  ((uint4*)(xg + (size_t)s_slot[k] * DD))[c] = src[c];
}

// ---------------- grouped bf16 GEMM, B^T layout, 128x128 tile, BK=32 ----------------
// MODE 0: C = silu(A @ B^T) -> bf16 Hg    MODE 1: C = (A @ B^T) * slot_w[row] -> fp32 Og
template<int KDIM, int NDIM, int MODE>
__global__ __launch_bounds__(256) void k_gemm(
    const unsigned short* __restrict__ Ag,
    const unsigned short* __restrict__ Bw,
    const int* __restrict__ counts, const int* __restrict__ bases,
    const float* __restrict__ slot_w,
    void* __restrict__ Cout)
{
  constexpr int NT = NDIM / 128;
  const int bpe = 16 * NT;
  const int e   = blockIdx.x / bpe;
  const int rem = blockIdx.x - e * bpe;
  const int mt  = rem / NT;
  const int nt  = rem - mt * NT;
  const int M = counts[e];
  if (mt * 128 >= M) return;
  const int sbase = bases[e];

  __shared__ __align__(16) unsigned short As[128 * 32];
  __shared__ __align__(16) unsigned short Bs[128 * 32];

  const int tid = threadIdx.x;
  const int l = tid & 63;
  const int w = tid >> 6;
  const int wm = (w >> 1) * 64, wn = (w & 1) * 64;
  const int lrow = l & 15, lk = (l >> 4) * 8;

  const unsigned short* A0 = Ag + (size_t)(sbase + mt * 128) * KDIM;
  const unsigned short* B0 = Bw + (size_t)e * NDIM * KDIM + (size_t)(nt * 128) * KDIM;

  floatx4 acc[4][4] = {};

  for (int k0 = 0; k0 < KDIM; k0 += 32){
    // stage 128x32 bf16 A and B tiles: 512 chunks of 16B each, 2 per thread
    #pragma unroll
    for (int i = 0; i < 2; i++){
      const int c = tid + i * 256;
      const int row = c >> 2, kc = c & 3;
      const unsigned short* ga = A0 + (size_t)row * KDIM + k0 + kc * 8;
      const unsigned short* gb = B0 + (size_t)row * KDIM + k0 + kc * 8;
      __builtin_amdgcn_global_load_lds(
          (__attribute__((address_space(1))) unsigned int*)ga,
          (__attribute__((address_space(3))) unsigned int*)(As + c * 8), 16, 0, 0);
      __builtin_amdgcn_global_load_lds(
          (__attribute__((address_space(1))) unsigned int*)gb,
          (__attribute__((address_space(3))) unsigned int*)(Bs + c * 8), 16, 0, 0);
    }
    __syncthreads();
    bf16x8 af[4], bfv[4];
    #pragma unroll
    for (int mi = 0; mi < 4; mi++)
      af[mi] = *(const bf16x8*)(As + (wm + mi * 16 + lrow) * 32 + lk);
    #pragma unroll
    for (int ni = 0; ni < 4; ni++)
      bfv[ni] = *(const bf16x8*)(Bs + (wn + ni * 16 + lrow) * 32 + lk);
    #pragma unroll
    for (int mi = 0; mi < 4; mi++)
      #pragma unroll
      for (int ni = 0; ni < 4; ni++)
        acc[mi][ni] = __builtin_amdgcn_mfma_f32_16x16x32_bf16(af[mi], bfv[ni], acc[mi][ni], 0, 0, 0);
    __syncthreads();
  }

  // epilogue: C/D layout col = lane&15, row = (lane>>4)*4 + r
  const int rb = (l >> 4) * 4;
  #pragma unroll
  for (int mi = 0; mi < 4; mi++){
    #pragma unroll
    for (int r = 0; r < 4; r++){
      const int row = mt * 128 + wm + mi * 16 + rb + r;
      if (row < M){
        #pragma unroll
        for (int ni = 0; ni < 4; ni++){
          const int col = nt * 128 + wn + ni * 16 + (l & 15);
          const float v = acc[mi][ni][r];
          if (MODE == 0){
            const float s = v / (1.f + __expf(-v));   // silu
            ((unsigned short*)Cout)[(size_t)(sbase + row) * NDIM + col] = f2bf(s);
          } else {
            const float wgt = slot_w[sbase + row];
            ((float*)Cout)[(size_t)(sbase + row) * NDIM + col] = v * wgt;
          }
        }
      }
    }
  }
}

// ---------------- residual combine ----------------
__global__ __launch_bounds__(256) void k_combine(
    const float* __restrict__ x, const float* __restrict__ Og,
    const int* __restrict__ slots_of, const float* __restrict__ scale,
    float* __restrict__ out)
{
  const int i = blockIdx.x * 256 + threadIdx.x;   // over T*D/4
  const int t = i >> 8;
  const int j = i & 255;
  const int s0 = slots_of[2*t], s1 = slots_of[2*t+1];
  const float4 a = ((const float4*)(Og + (size_t)s0 * DD))[j];
  const float4 b = ((const float4*)(Og + (size_t)s1 * DD))[j];
  const float4 xv = ((const float4*)x)[i];
  const float sc = 1.f / (1.f + __expf(-scale[0]));
  float4 o;
  o.x = xv.x + sc * (a.x + b.x);
  o.y = xv.y + sc * (a.y + b.y);
  o.z = xv.z + sc * (a.z + b.z);
  o.w = xv.w + sc * (a.w + b.w);
  ((float4*)out)[i] = o;
}

extern "C" void kernel_launch(void* const* d_in, const int* in_sizes, int n_in,
                              void* d_out, int out_size, void* d_ws, size_t ws_size,
                              hipStream_t stream)
{
  const float* x     = (const float*)d_in[0];   // [2,1024,1024]
  const float* gw    = (const float*)d_in[1];   // [8,1024]
  const float* w1    = (const float*)d_in[2];   // [8,2048,1024]
  const float* w2    = (const float*)d_in[3];   // [8,1024,2048]
  const float* nw    = (const float*)d_in[4];   // [1024]
  const float* scale = (const float*)d_in[5];   // [1]
  float* out = (float*)d_out;                   // 2097152 + 1 (lb loss)

  char* ws = (char*)d_ws;
  int*   counts  = (int*)(ws + 0);
  int*   bases   = (int*)(ws + 32);
  int*   ctr     = (int*)(ws + 64);
  int*   cnt1    = (int*)(ws + 96);
  float* sumprob = (float*)(ws + 128);
  int*   topk_id = (int*)(ws + 256);
  float* topk_w  = (float*)(ws + 256 + 16384);
  int*   slots_of= (int*)(ws + 256 + 2*16384);
  float* slot_w  = (float*)(ws + 256 + 3*16384);
  unsigned short* xn  = (unsigned short*)(ws + 131072);
  unsigned short* xg  = xn + (size_t)T_TOK * DD;
  unsigned short* Hg  = xg + (size_t)SLOTPAD * DD;
  float*          Og  = (float*)(Hg + (size_t)SLOTPAD * FF);
  unsigned short* w1b = (unsigned short*)(Og + (size_t)SLOTPAD * DD);
  unsigned short* w2b = w1b + (size_t)EE * FF * DD;

  hipMemsetAsync(ws, 0, 256, stream);
  k_cvt_bf16<<<8192, 256, 0, stream>>>(w1, w1b, EE*FF*DD/4);
  k_cvt_bf16<<<8192, 256, 0, stream>>>(w2, w2b, EE*DD*FF/4);
  k_rms_router<<<T_TOK, 256, 0, stream>>>(x, gw, nw, xn, topk_id, topk_w, counts, cnt1, sumprob);
  k_prep<<<1, 64, 0, stream>>>(counts, bases, cnt1, sumprob, out + (size_t)T_TOK * DD);
  k_assign<<<T_TOK, 256, 0, stream>>>(topk_id, topk_w, bases, ctr, slots_of, slot_w, xn, xg);
  k_gemm<1024, 2048, 0><<<EE * 16 * (FF/128), 256, 0, stream>>>(xg, w1b, counts, bases, nullptr, Hg);
  k_gemm<2048, 1024, 1><<<EE * 16 * (DD/128), 256, 0, stream>>>(Hg, w2b, counts, bases, slot_w, Og);
  k_combine<<<T_TOK * DD / 4 / 256, 256, 0, stream>>>(x, Og, slots_of, scale, out);
}

// Round 2
// 403.527 us; speedup vs baseline: 1.4954x; 1.4954x over previous
//
#include <hip/hip_runtime.h>
#include <stdint.h>

#define T_TOK 2048
#define DD 1024
#define EE 8
#define FF 2048
#define SLOTPAD 4224   // T*K + 128 pad rows

typedef __attribute__((ext_vector_type(8))) __bf16 bf16x8;
typedef __attribute__((ext_vector_type(4))) float floatx4;

__device__ __forceinline__ unsigned short f2bf(float f){
  union { float f; unsigned u; } v; v.f = f;
  unsigned r = v.u + 0x7fffu + ((v.u >> 16) & 1u);
  return (unsigned short)(r >> 16);
}

// ---------------- fp32 -> bf16 weight convert ----------------
__global__ __launch_bounds__(256) void k_cvt_bf16(const float* __restrict__ in,
    unsigned short* __restrict__ out, int n4)
{
  int i = blockIdx.x * 256 + threadIdx.x;
  const int stride = gridDim.x * 256;
  for (; i < n4; i += stride){
    const float4 v = ((const float4*)in)[i];
    ushort4 o; o.x = f2bf(v.x); o.y = f2bf(v.y); o.z = f2bf(v.z); o.w = f2bf(v.w);
    ((ushort4*)out)[i] = o;
  }
}

// ---------------- RMSNorm + router (one block per token, NO global atomics) ----
__global__ __launch_bounds__(256) void k_rms_router(
    const float* __restrict__ x, const float* __restrict__ gw,
    const float* __restrict__ nw,
    unsigned short* __restrict__ xn,
    int* __restrict__ topk_id, float* __restrict__ topk_w,
    float* __restrict__ probbuf)
{
  const int t = blockIdx.x, tid = threadIdx.x;
  const float4 xv = ((const float4*)(x + (size_t)t * DD))[tid];
  float ss = xv.x*xv.x + xv.y*xv.y + xv.z*xv.z + xv.w*xv.w;
  #pragma unroll
  for (int o = 32; o > 0; o >>= 1) ss += __shfl_down(ss, o);
  __shared__ float s_ss[4];
  __shared__ float s_p[4][8];
  if ((tid & 63) == 0) s_ss[tid >> 6] = ss;
  __syncthreads();
  const float tot = s_ss[0] + s_ss[1] + s_ss[2] + s_ss[3];
  const float inv = rsqrtf(tot * (1.0f / DD) + 1.1920929e-7f);
  const float4 nv = ((const float4*)nw)[tid];
  float4 xnv;
  xnv.x = xv.x*inv*nv.x; xnv.y = xv.y*inv*nv.y;
  xnv.z = xv.z*inv*nv.z; xnv.w = xv.w*inv*nv.w;
  ushort4 bv; bv.x = f2bf(xnv.x); bv.y = f2bf(xnv.y); bv.z = f2bf(xnv.z); bv.w = f2bf(xnv.w);
  ((ushort4*)(xn + (size_t)t * DD))[tid] = bv;
  float p[8];
  #pragma unroll
  for (int e = 0; e < 8; e++){
    const float4 g = ((const float4*)(gw + e * DD))[tid];
    p[e] = xnv.x*g.x + xnv.y*g.y + xnv.z*g.z + xnv.w*g.w;
  }
  #pragma unroll
  for (int e = 0; e < 8; e++){
    #pragma unroll
    for (int o = 32; o > 0; o >>= 1) p[e] += __shfl_down(p[e], o);
  }
  if ((tid & 63) == 0){
    #pragma unroll
    for (int e = 0; e < 8; e++) s_p[tid >> 6][e] = p[e];
  }
  __syncthreads();
  if (tid == 0){
    float lg[8], pr[8];
    #pragma unroll
    for (int e = 0; e < 8; e++) lg[e] = s_p[0][e] + s_p[1][e] + s_p[2][e] + s_p[3][e];
    float mx = lg[0];
    for (int e = 1; e < 8; e++) mx = fmaxf(mx, lg[e]);
    float sum = 0.f;
    for (int e = 0; e < 8; e++){ pr[e] = __expf(lg[e] - mx); sum += pr[e]; }
    const float is = 1.f / sum;
    for (int e = 0; e < 8; e++) pr[e] *= is;
    #pragma unroll
    for (int e = 0; e < 8; e++) probbuf[t * 8 + e] = pr[e];
    int e1 = 0;
    for (int e = 1; e < 8; e++) if (pr[e] > pr[e1]) e1 = e;       // first max (tie: lower idx)
    int e2 = (e1 == 0) ? 1 : 0;
    for (int e = 0; e < 8; e++) if (e != e1 && e != e2 && pr[e] > pr[e2]) e2 = e;
    const float wsum = fmaxf(pr[e1] + pr[e2], 1e-6f);
    topk_id[2*t] = e1; topk_id[2*t+1] = e2;
    topk_w[2*t] = pr[e1] / wsum; topk_w[2*t+1] = pr[e2] / wsum;
  }
}

// ---------------- single-block stats: counts, bases, lb loss ----------------
__global__ __launch_bounds__(256) void k_stats(
    const int* __restrict__ topk_id, const float* __restrict__ probbuf,
    int* __restrict__ counts, int* __restrict__ bases,
    float* __restrict__ lb_out)
{
  const int tid = threadIdx.x;
  int lc[8] = {}, lc1[8] = {};
  float lsp[8] = {};
  for (int t = tid; t < T_TOK; t += 256){
    const int e1 = topk_id[2*t], e2 = topk_id[2*t+1];
    #pragma unroll
    for (int e = 0; e < 8; e++){
      lc[e]  += (e1 == e) + (e2 == e);
      lc1[e] += (e1 == e);
      lsp[e] += probbuf[t * 8 + e];
    }
  }
  #pragma unroll
  for (int e = 0; e < 8; e++){
    #pragma unroll
    for (int o = 32; o > 0; o >>= 1){
      lc[e]  += __shfl_down(lc[e], o);
      lc1[e] += __shfl_down(lc1[e], o);
      lsp[e] += __shfl_down(lsp[e], o);
    }
  }
  __shared__ int   s_c[4][8], s_c1[4][8];
  __shared__ float s_s[4][8];
  if ((tid & 63) == 0){
    const int w = tid >> 6;
    #pragma unroll
    for (int e = 0; e < 8; e++){ s_c[w][e] = lc[e]; s_c1[w][e] = lc1[e]; s_s[w][e] = lsp[e]; }
  }
  __syncthreads();
  if (tid == 0){
    int b = 0; float lb = 0.f;
    for (int e = 0; e < 8; e++){
      const int   c  = s_c[0][e] + s_c[1][e] + s_c[2][e] + s_c[3][e];
      const int   c1 = s_c1[0][e] + s_c1[1][e] + s_c1[2][e] + s_c1[3][e];
      const float sp = s_s[0][e] + s_s[1][e] + s_s[2][e] + s_s[3][e];
      counts[e] = c; bases[e] = b; b += c;
      lb += (float)c1 * sp;
    }
    lb_out[0] = 8.f * lb * (1.f / ((float)T_TOK * (float)T_TOK));
  }
}

// ---------------- slot assignment + row gather ----------------
__global__ __launch_bounds__(256) void k_assign(
    const int* __restrict__ topk_id, const float* __restrict__ topk_w,
    const int* __restrict__ bases, int* __restrict__ ctr,
    int* __restrict__ slots_of, float* __restrict__ slot_w,
    const unsigned short* __restrict__ xn, unsigned short* __restrict__ xg)
{
  const int t = blockIdx.x, tid = threadIdx.x;
  __shared__ int s_slot[2];
  if (tid < 2){
    const int e = topk_id[2*t + tid];
    const int pos = atomicAdd(&ctr[e], 1);
    const int slot = bases[e] + pos;
    s_slot[tid] = slot;
    slot_w[slot] = topk_w[2*t + tid];
    slots_of[2*t + tid] = slot;
  }
  __syncthreads();
  const uint4* src = (const uint4*)(xn + (size_t)t * DD);
  const int k = tid >> 7, c = tid & 127;          // 128 x 16B per row, 2 rows per block
  ((uint4*)(xg + (size_t)s_slot[k] * DD))[c] = src[c];
}

// ---------------- grouped bf16 GEMM, B^T layout, 128x128 tile, BK=32 ----------------
// MODE 0: C = silu(A @ B^T) -> bf16 Hg    MODE 1: C = (A @ B^T) * slot_w[row] -> fp32 Og
template<int KDIM, int NDIM, int MODE>
__global__ __launch_bounds__(256) void k_gemm(
    const unsigned short* __restrict__ Ag,
    const unsigned short* __restrict__ Bw,
    const int* __restrict__ counts, const int* __restrict__ bases,
    const float* __restrict__ slot_w,
    void* __restrict__ Cout)
{
  constexpr int NT = NDIM / 128;
  const int bpe = 16 * NT;
  const int e   = blockIdx.x / bpe;
  const int rem = blockIdx.x - e * bpe;
  const int mt  = rem / NT;
  const int nt  = rem - mt * NT;
  const int M = counts[e];
  if (mt * 128 >= M) return;
  const int sbase = bases[e];

  __shared__ __align__(16) unsigned short As[128 * 32];
  __shared__ __align__(16) unsigned short Bs[128 * 32];

  const int tid = threadIdx.x;
  const int l = tid & 63;
  const int w = tid >> 6;
  const int wm = (w >> 1) * 64, wn = (w & 1) * 64;
  const int lrow = l & 15, lk = (l >> 4) * 8;

  const unsigned short* A0 = Ag + (size_t)(sbase + mt * 128) * KDIM;
  const unsigned short* B0 = Bw + (size_t)e * NDIM * KDIM + (size_t)(nt * 128) * KDIM;

  floatx4 acc[4][4] = {};

  for (int k0 = 0; k0 < KDIM; k0 += 32){
    // stage 128x32 bf16 A and B tiles: 512 chunks of 16B each, 2 per thread
    #pragma unroll
    for (int i = 0; i < 2; i++){
      const int c = tid + i * 256;
      const int row = c >> 2, kc = c & 3;
      const unsigned short* ga = A0 + (size_t)row * KDIM + k0 + kc * 8;
      const unsigned short* gb = B0 + (size_t)row * KDIM + k0 + kc * 8;
      __builtin_amdgcn_global_load_lds(
          (__attribute__((address_space(1))) unsigned int*)ga,
          (__attribute__((address_space(3))) unsigned int*)(As + c * 8), 16, 0, 0);
      __builtin_amdgcn_global_load_lds(
          (__attribute__((address_space(1))) unsigned int*)gb,
          (__attribute__((address_space(3))) unsigned int*)(Bs + c * 8), 16, 0, 0);
    }
    __syncthreads();
    bf16x8 af[4], bfv[4];
    #pragma unroll
    for (int mi = 0; mi < 4; mi++)
      af[mi] = *(const bf16x8*)(As + (wm + mi * 16 + lrow) * 32 + lk);
    #pragma unroll
    for (int ni = 0; ni < 4; ni++)
      bfv[ni] = *(const bf16x8*)(Bs + (wn + ni * 16 + lrow) * 32 + lk);
    #pragma unroll
    for (int mi = 0; mi < 4; mi++)
      #pragma unroll
      for (int ni = 0; ni < 4; ni++)
        acc[mi][ni] = __builtin_amdgcn_mfma_f32_16x16x32_bf16(af[mi], bfv[ni], acc[mi][ni], 0, 0, 0);
    __syncthreads();
  }

  // epilogue: C/D layout col = lane&15, row = (lane>>4)*4 + r
  const int rb = (l >> 4) * 4;
  #pragma unroll
  for (int mi = 0; mi < 4; mi++){
    #pragma unroll
    for (int r = 0; r < 4; r++){
      const int row = mt * 128 + wm + mi * 16 + rb + r;
      if (row < M){
        #pragma unroll
        for (int ni = 0; ni < 4; ni++){
          const int col = nt * 128 + wn + ni * 16 + (l & 15);
          const float v = acc[mi][ni][r];
          if (MODE == 0){
            const float s = v / (1.f + __expf(-v));   // silu
            ((unsigned short*)Cout)[(size_t)(sbase + row) * NDIM + col] = f2bf(s);
          } else {
            const float wgt = slot_w[sbase + row];
            ((float*)Cout)[(size_t)(sbase + row) * NDIM + col] = v * wgt;
          }
        }
      }
    }
  }
}

// ---------------- residual combine ----------------
__global__ __launch_bounds__(256) void k_combine(
    const float* __restrict__ x, const float* __restrict__ Og,
    const int* __restrict__ slots_of, const float* __restrict__ scale,
    float* __restrict__ out)
{
  const int i = blockIdx.x * 256 + threadIdx.x;   // over T*D/4
  const int t = i >> 8;
  const int j = i & 255;
  const int s0 = slots_of[2*t], s1 = slots_of[2*t+1];
  const float4 a = ((const float4*)(Og + (size_t)s0 * DD))[j];
  const float4 b = ((const float4*)(Og + (size_t)s1 * DD))[j];
  const float4 xv = ((const float4*)x)[i];
  const float sc = 1.f / (1.f + __expf(-scale[0]));
  float4 o;
  o.x = xv.x + sc * (a.x + b.x);
  o.y = xv.y + sc * (a.y + b.y);
  o.z = xv.z + sc * (a.z + b.z);
  o.w = xv.w + sc * (a.w + b.w);
  ((float4*)out)[i] = o;
}

extern "C" void kernel_launch(void* const* d_in, const int* in_sizes, int n_in,
                              void* d_out, int out_size, void* d_ws, size_t ws_size,
                              hipStream_t stream)
{
  const float* x     = (const float*)d_in[0];   // [2,1024,1024]
  const float* gw    = (const float*)d_in[1];   // [8,1024]
  const float* w1    = (const float*)d_in[2];   // [8,2048,1024]
  const float* w2    = (const float*)d_in[3];   // [8,1024,2048]
  const float* nw    = (const float*)d_in[4];   // [1024]
  const float* scale = (const float*)d_in[5];   // [1]
  float* out = (float*)d_out;                   // 2097152 + 1 (lb loss)

  char* ws = (char*)d_ws;
  int*   counts  = (int*)(ws + 0);
  int*   bases   = (int*)(ws + 32);
  int*   ctr     = (int*)(ws + 64);
  int*   topk_id = (int*)(ws + 1024);            // 16 KB
  float* topk_w  = (float*)(ws + 20480);         // 16 KB
  int*   slots_of= (int*)(ws + 40960);           // 16 KB
  float* slot_w  = (float*)(ws + 61440);         // 16 KB
  float* probbuf = (float*)(ws + 81920);         // 64 KB
  unsigned short* xn  = (unsigned short*)(ws + 262144);
  unsigned short* xg  = xn + (size_t)T_TOK * DD;
  unsigned short* Hg  = xg + (size_t)SLOTPAD * DD;
  float*          Og  = (float*)(Hg + (size_t)SLOTPAD * FF);
  unsigned short* w1b = (unsigned short*)(Og + (size_t)SLOTPAD * DD);
  unsigned short* w2b = w1b + (size_t)EE * FF * DD;

  hipMemsetAsync(ws, 0, 256, stream);
  k_cvt_bf16<<<8192, 256, 0, stream>>>(w1, w1b, EE*FF*DD/4);
  k_cvt_bf16<<<8192, 256, 0, stream>>>(w2, w2b, EE*DD*FF/4);
  k_rms_router<<<T_TOK, 256, 0, stream>>>(x, gw, nw, xn, topk_id, topk_w, probbuf);
  k_stats<<<1, 256, 0, stream>>>(topk_id, probbuf, counts, bases, out + (size_t)T_TOK * DD);
  k_assign<<<T_TOK, 256, 0, stream>>>(topk_id, topk_w, bases, ctr, slots_of, slot_w, xn, xg);
  k_gemm<1024, 2048, 0><<<EE * 16 * (FF/128), 256, 0, stream>>>(xg, w1b, counts, bases, nullptr, Hg);
  k_gemm<2048, 1024, 1><<<EE * 16 * (DD/128), 256, 0, stream>>>(Hg, w2b, counts, bases, slot_w, Og);
  k_combine<<<T_TOK * DD / 4 / 256, 256, 0, stream>>>(x, Og, slots_of, scale, out);
}

// Round 3
// 283.676 us; speedup vs baseline: 2.1272x; 1.4225x over previous
//
#include <hip/hip_runtime.h>
#include <stdint.h>

#define T_TOK 2048
#define DD 1024
#define EE 8
#define FF 2048
#define NSLOT 4096     // T*K
#define SLOTPAD 4224   // NSLOT + 128 pad rows

typedef __attribute__((ext_vector_type(8))) __bf16 bf16x8;
typedef __attribute__((ext_vector_type(4))) float floatx4;

__device__ __forceinline__ unsigned short f2bf(float f){
  union { float f; unsigned u; } v; v.f = f;
  unsigned r = v.u + 0x7fffu + ((v.u >> 16) & 1u);
  return (unsigned short)(r >> 16);
}

// ---------------- fp32 -> bf16 weight convert ----------------
__global__ __launch_bounds__(256) void k_cvt_bf16(const float* __restrict__ in,
    unsigned short* __restrict__ out, int n4)
{
  int i = blockIdx.x * 256 + threadIdx.x;
  const int stride = gridDim.x * 256;
  for (; i < n4; i += stride){
    const float4 v = ((const float4*)in)[i];
    ushort4 o; o.x = f2bf(v.x); o.y = f2bf(v.y); o.z = f2bf(v.z); o.w = f2bf(v.w);
    ((ushort4*)out)[i] = o;
  }
}

// ---------------- RMSNorm + router (one block per token, NO global atomics) ----
__global__ __launch_bounds__(256) void k_rms_router(
    const float* __restrict__ x, const float* __restrict__ gw,
    const float* __restrict__ nw,
    unsigned short* __restrict__ xn,
    int* __restrict__ topk_id, float* __restrict__ topk_w,
    float* __restrict__ probbuf)
{
  const int t = blockIdx.x, tid = threadIdx.x;
  const float4 xv = ((const float4*)(x + (size_t)t * DD))[tid];
  float ss = xv.x*xv.x + xv.y*xv.y + xv.z*xv.z + xv.w*xv.w;
  #pragma unroll
  for (int o = 32; o > 0; o >>= 1) ss += __shfl_down(ss, o);
  __shared__ float s_ss[4];
  __shared__ float s_p[4][8];
  if ((tid & 63) == 0) s_ss[tid >> 6] = ss;
  __syncthreads();
  const float tot = s_ss[0] + s_ss[1] + s_ss[2] + s_ss[3];
  const float inv = rsqrtf(tot * (1.0f / DD) + 1.1920929e-7f);
  const float4 nv = ((const float4*)nw)[tid];
  float4 xnv;
  xnv.x = xv.x*inv*nv.x; xnv.y = xv.y*inv*nv.y;
  xnv.z = xv.z*inv*nv.z; xnv.w = xv.w*inv*nv.w;
  ushort4 bv; bv.x = f2bf(xnv.x); bv.y = f2bf(xnv.y); bv.z = f2bf(xnv.z); bv.w = f2bf(xnv.w);
  ((ushort4*)(xn + (size_t)t * DD))[tid] = bv;
  float p[8];
  #pragma unroll
  for (int e = 0; e < 8; e++){
    const float4 g = ((const float4*)(gw + e * DD))[tid];
    p[e] = xnv.x*g.x + xnv.y*g.y + xnv.z*g.z + xnv.w*g.w;
  }
  #pragma unroll
  for (int e = 0; e < 8; e++){
    #pragma unroll
    for (int o = 32; o > 0; o >>= 1) p[e] += __shfl_down(p[e], o);
  }
  if ((tid & 63) == 0){
    #pragma unroll
    for (int e = 0; e < 8; e++) s_p[tid >> 6][e] = p[e];
  }
  __syncthreads();
  if (tid == 0){
    float lg[8], pr[8];
    #pragma unroll
    for (int e = 0; e < 8; e++) lg[e] = s_p[0][e] + s_p[1][e] + s_p[2][e] + s_p[3][e];
    float mx = lg[0];
    for (int e = 1; e < 8; e++) mx = fmaxf(mx, lg[e]);
    float sum = 0.f;
    for (int e = 0; e < 8; e++){ pr[e] = __expf(lg[e] - mx); sum += pr[e]; }
    const float is = 1.f / sum;
    for (int e = 0; e < 8; e++) pr[e] *= is;
    #pragma unroll
    for (int e = 0; e < 8; e++) probbuf[t * 8 + e] = pr[e];
    int e1 = 0;
    for (int e = 1; e < 8; e++) if (pr[e] > pr[e1]) e1 = e;       // first max (tie: lower idx)
    int e2 = (e1 == 0) ? 1 : 0;
    for (int e = 0; e < 8; e++) if (e != e1 && e != e2 && pr[e] > pr[e2]) e2 = e;
    const float wsum = fmaxf(pr[e1] + pr[e2], 1e-6f);
    topk_id[2*t] = e1; topk_id[2*t+1] = e2;
    topk_w[2*t] = pr[e1] / wsum; topk_w[2*t+1] = pr[e2] / wsum;
  }
}

// ------- single-block: counts, bases, lb loss, deterministic slot assignment ----
// Thread i owns tokens [i*8, i*8+8). Hillis-Steele scan over per-thread expert
// counts gives each thread its exclusive per-expert rank base -> slot ids
// without any atomics.
__global__ __launch_bounds__(256) void k_stats(
    const int* __restrict__ topk_id, const float* __restrict__ topk_w,
    const float* __restrict__ probbuf,
    int* __restrict__ counts, int* __restrict__ bases,
    int* __restrict__ slots_of, int* __restrict__ tok_of,
    float* __restrict__ slot_w,
    float* __restrict__ lb_out)
{
  const int tid = threadIdx.x;
  __shared__ int s_scan[256][8];
  __shared__ int s_base[8];

  int ids[16];
  int lc[8] = {}, lc1[8] = {};
  float lsp[8] = {};
  #pragma unroll
  for (int j = 0; j < 8; j++){
    const int t = tid * 8 + j;
    const int e1 = topk_id[2*t], e2 = topk_id[2*t+1];
    ids[2*j] = e1; ids[2*j+1] = e2;
    lc[e1]++; lc[e2]++; lc1[e1]++;
    const float4 p0 = ((const float4*)(probbuf + t * 8))[0];
    const float4 p1 = ((const float4*)(probbuf + t * 8))[1];
    lsp[0] += p0.x; lsp[1] += p0.y; lsp[2] += p0.z; lsp[3] += p0.w;
    lsp[4] += p1.x; lsp[5] += p1.y; lsp[6] += p1.z; lsp[7] += p1.w;
  }
  #pragma unroll
  for (int e = 0; e < 8; e++) s_scan[tid][e] = lc[e];
  __syncthreads();
  // inclusive scan over 256 threads, 8 experts in parallel
  for (int off = 1; off < 256; off <<= 1){
    int v[8];
    if (tid >= off){
      #pragma unroll
      for (int e = 0; e < 8; e++) v[e] = s_scan[tid - off][e];
    }
    __syncthreads();
    if (tid >= off){
      #pragma unroll
      for (int e = 0; e < 8; e++) s_scan[tid][e] += v[e];
    }
    __syncthreads();
  }
  // reduce lc1 / lsp for lb loss (wave shuffle + LDS)
  int   rc1[8]; float rsp[8];
  #pragma unroll
  for (int e = 0; e < 8; e++){ rc1[e] = lc1[e]; rsp[e] = lsp[e]; }
  #pragma unroll
  for (int e = 0; e < 8; e++){
    #pragma unroll
    for (int o = 32; o > 0; o >>= 1){
      rc1[e] += __shfl_down(rc1[e], o);
      rsp[e] += __shfl_down(rsp[e], o);
    }
  }
  __shared__ int   s_c1[4][8];
  __shared__ float s_sp[4][8];
  if ((tid & 63) == 0){
    const int w = tid >> 6;
    #pragma unroll
    for (int e = 0; e < 8; e++){ s_c1[w][e] = rc1[e]; s_sp[w][e] = rsp[e]; }
  }
  __syncthreads();
  if (tid == 0){
    int b = 0; float lb = 0.f;
    for (int e = 0; e < 8; e++){
      const int tot = s_scan[255][e];
      counts[e] = tot; bases[e] = b; s_base[e] = b; b += tot;
      const int   c1 = s_c1[0][e] + s_c1[1][e] + s_c1[2][e] + s_c1[3][e];
      const float sp = s_sp[0][e] + s_sp[1][e] + s_sp[2][e] + s_sp[3][e];
      lb += (float)c1 * sp;
    }
    lb_out[0] = 8.f * lb * (1.f / ((float)T_TOK * (float)T_TOK));
  }
  __syncthreads();
  int rank[8];
  #pragma unroll
  for (int e = 0; e < 8; e++) rank[e] = s_scan[tid][e] - lc[e];   // exclusive prefix
  #pragma unroll
  for (int j = 0; j < 8; j++){
    const int t = tid * 8 + j;
    #pragma unroll
    for (int k = 0; k < 2; k++){
      const int e = ids[2*j + k];
      const int slot = s_base[e] + rank[e]++;
      slots_of[2*t + k] = slot;
      tok_of[slot] = t;
      slot_w[slot] = topk_w[2*t + k];
    }
  }
}

// ---------------- grouped bf16 GEMM, B^T layout, 128x128 tile, BK=32 ----------------
// MODE 0 (+indirect A): C = silu(xn[tok_of[slot]] @ B^T) -> bf16 Hg
// MODE 1 (direct A):    C = (A @ B^T) * slot_w[row] -> fp32 Og
template<int KDIM, int NDIM, int MODE>
__global__ __launch_bounds__(256) void k_gemm(
    const unsigned short* __restrict__ Ag,
    const unsigned short* __restrict__ Bw,
    const int* __restrict__ counts, const int* __restrict__ bases,
    const int* __restrict__ tok_of,
    const float* __restrict__ slot_w,
    void* __restrict__ Cout)
{
  constexpr int NT = NDIM / 128;
  const int bpe = 16 * NT;
  const int e   = blockIdx.x / bpe;
  const int rem = blockIdx.x - e * bpe;
  const int mt  = rem / NT;
  const int nt  = rem - mt * NT;
  const int M = counts[e];
  if (mt * 128 >= M) return;
  const int sbase = bases[e];

  __shared__ __align__(16) unsigned short As[128 * 32];
  __shared__ __align__(16) unsigned short Bs[128 * 32];

  const int tid = threadIdx.x;
  const int l = tid & 63;
  const int w = tid >> 6;
  const int wm = (w >> 1) * 64, wn = (w & 1) * 64;
  const int lrow = l & 15, lk = (l >> 4) * 8;

  // A row sources (hoisted out of K-loop): 2 staged rows per thread
  const unsigned short* arow[2];
  #pragma unroll
  for (int i = 0; i < 2; i++){
    const int c = tid + i * 256;
    const int row = c >> 2;
    if (MODE == 0){
      const int slot = min(sbase + mt * 128 + row, NSLOT - 1);
      arow[i] = Ag + (size_t)tok_of[slot] * KDIM;
    } else {
      arow[i] = Ag + (size_t)(sbase + mt * 128 + row) * KDIM;
    }
  }
  const unsigned short* B0 = Bw + (size_t)e * NDIM * KDIM + (size_t)(nt * 128) * KDIM;

  floatx4 acc[4][4] = {};

  for (int k0 = 0; k0 < KDIM; k0 += 32){
    #pragma unroll
    for (int i = 0; i < 2; i++){
      const int c = tid + i * 256;
      const int row = c >> 2, kc = c & 3;
      const unsigned short* ga = arow[i] + k0 + kc * 8;
      const unsigned short* gb = B0 + (size_t)row * KDIM + k0 + kc * 8;
      __builtin_amdgcn_global_load_lds(
          (__attribute__((address_space(1))) unsigned int*)ga,
          (__attribute__((address_space(3))) unsigned int*)(As + c * 8), 16, 0, 0);
      __builtin_amdgcn_global_load_lds(
          (__attribute__((address_space(1))) unsigned int*)gb,
          (__attribute__((address_space(3))) unsigned int*)(Bs + c * 8), 16, 0, 0);
    }
    __syncthreads();
    bf16x8 af[4], bfv[4];
    #pragma unroll
    for (int mi = 0; mi < 4; mi++)
      af[mi] = *(const bf16x8*)(As + (wm + mi * 16 + lrow) * 32 + lk);
    #pragma unroll
    for (int ni = 0; ni < 4; ni++)
      bfv[ni] = *(const bf16x8*)(Bs + (wn + ni * 16 + lrow) * 32 + lk);
    #pragma unroll
    for (int mi = 0; mi < 4; mi++)
      #pragma unroll
      for (int ni = 0; ni < 4; ni++)
        acc[mi][ni] = __builtin_amdgcn_mfma_f32_16x16x32_bf16(af[mi], bfv[ni], acc[mi][ni], 0, 0, 0);
    __syncthreads();
  }

  // epilogue: C/D layout col = lane&15, row = (lane>>4)*4 + r
  const int rb = (l >> 4) * 4;
  #pragma unroll
  for (int mi = 0; mi < 4; mi++){
    #pragma unroll
    for (int r = 0; r < 4; r++){
      const int row = mt * 128 + wm + mi * 16 + rb + r;
      if (row < M){
        #pragma unroll
        for (int ni = 0; ni < 4; ni++){
          const int col = nt * 128 + wn + ni * 16 + (l & 15);
          const float v = acc[mi][ni][r];
          if (MODE == 0){
            const float s = v / (1.f + __expf(-v));   // silu
            ((unsigned short*)Cout)[(size_t)(sbase + row) * NDIM + col] = f2bf(s);
          } else {
            const float wgt = slot_w[sbase + row];
            ((float*)Cout)[(size_t)(sbase + row) * NDIM + col] = v * wgt;
          }
        }
      }
    }
  }
}

// ---------------- residual combine ----------------
__global__ __launch_bounds__(256) void k_combine(
    const float* __restrict__ x, const float* __restrict__ Og,
    const int* __restrict__ slots_of, const float* __restrict__ scale,
    float* __restrict__ out)
{
  const int i = blockIdx.x * 256 + threadIdx.x;   // over T*D/4
  const int t = i >> 8;
  const int j = i & 255;
  const int s0 = slots_of[2*t], s1 = slots_of[2*t+1];
  const float4 a = ((const float4*)(Og + (size_t)s0 * DD))[j];
  const float4 b = ((const float4*)(Og + (size_t)s1 * DD))[j];
  const float4 xv = ((const float4*)x)[i];
  const float sc = 1.f / (1.f + __expf(-scale[0]));
  float4 o;
  o.x = xv.x + sc * (a.x + b.x);
  o.y = xv.y + sc * (a.y + b.y);
  o.z = xv.z + sc * (a.z + b.z);
  o.w = xv.w + sc * (a.w + b.w);
  ((float4*)out)[i] = o;
}

extern "C" void kernel_launch(void* const* d_in, const int* in_sizes, int n_in,
                              void* d_out, int out_size, void* d_ws, size_t ws_size,
                              hipStream_t stream)
{
  const float* x     = (const float*)d_in[0];   // [2,1024,1024]
  const float* gw    = (const float*)d_in[1];   // [8,1024]
  const float* w1    = (const float*)d_in[2];   // [8,2048,1024]
  const float* w2    = (const float*)d_in[3];   // [8,1024,2048]
  const float* nw    = (const float*)d_in[4];   // [1024]
  const float* scale = (const float*)d_in[5];   // [1]
  float* out = (float*)d_out;                   // 2097152 + 1 (lb loss)

  char* ws = (char*)d_ws;
  int*   counts  = (int*)(ws + 0);
  int*   bases   = (int*)(ws + 64);
  int*   topk_id = (int*)(ws + 1024);            // 16 KB
  float* topk_w  = (float*)(ws + 20480);         // 16 KB
  int*   slots_of= (int*)(ws + 40960);           // 16 KB
  float* slot_w  = (float*)(ws + 61440);         // 16 KB (SLOTPAD floats fits)
  int*   tok_of  = (int*)(ws + 81920);           // 16 KB
  float* probbuf = (float*)(ws + 102400);        // 64 KB
  unsigned short* xn  = (unsigned short*)(ws + 262144);
  unsigned short* Hg  = xn + (size_t)T_TOK * DD;
  float*          Og  = (float*)(Hg + (size_t)SLOTPAD * FF);
  unsigned short* w1b = (unsigned short*)(Og + (size_t)SLOTPAD * DD);
  unsigned short* w2b = w1b + (size_t)EE * FF * DD;

  k_cvt_bf16<<<8192, 256, 0, stream>>>(w1, w1b, EE*FF*DD/4);
  k_cvt_bf16<<<8192, 256, 0, stream>>>(w2, w2b, EE*DD*FF/4);
  k_rms_router<<<T_TOK, 256, 0, stream>>>(x, gw, nw, xn, topk_id, topk_w, probbuf);
  k_stats<<<1, 256, 0, stream>>>(topk_id, topk_w, probbuf, counts, bases,
                                 slots_of, tok_of, slot_w, out + (size_t)T_TOK * DD);
  k_gemm<1024, 2048, 0><<<EE * 16 * (FF/128), 256, 0, stream>>>(xn, w1b, counts, bases, tok_of, nullptr, Hg);
  k_gemm<2048, 1024, 1><<<EE * 16 * (DD/128), 256, 0, stream>>>(Hg, w2b, counts, bases, nullptr, slot_w, Og);
  k_combine<<<T_TOK * DD / 4 / 256, 256, 0, stream>>>(x, Og, slots_of, scale, out);
}

// Round 4
// 274.452 us; speedup vs baseline: 2.1987x; 1.0336x over previous
//
#include <hip/hip_runtime.h>
#include <stdint.h>

#define T_TOK 2048
#define DD 1024
#define EE 8
#define FF 2048
#define NSLOT 4096     // T*K
#define SLOTPAD 4224   // NSLOT + 128 pad rows
#define CVT_BLOCKS 6144

typedef __attribute__((ext_vector_type(8))) __bf16 bf16x8;
typedef __attribute__((ext_vector_type(4))) float floatx4;

__device__ __forceinline__ unsigned short f2bf(float f){
  union { float f; unsigned u; } v; v.f = f;
  unsigned r = v.u + 0x7fffu + ((v.u >> 16) & 1u);
  return (unsigned short)(r >> 16);
}

// ------- fused front: blocks [0,T_TOK) = RMSNorm+router; rest = w1/w2 fp32->bf16 ----
__global__ __launch_bounds__(256) void k_front(
    const float* __restrict__ x, const float* __restrict__ gw,
    const float* __restrict__ nw,
    const float* __restrict__ w1, const float* __restrict__ w2,
    unsigned short* __restrict__ xn,
    int* __restrict__ topk_id, float* __restrict__ topk_w,
    float* __restrict__ probbuf,
    unsigned short* __restrict__ w1b, unsigned short* __restrict__ w2b)
{
  const int tid = threadIdx.x;
  if (blockIdx.x >= T_TOK){
    // ---- weight convert part ----
    const int n4 = EE * FF * DD / 4;
    int i = (blockIdx.x - T_TOK) * 256 + tid;
    const int stride = CVT_BLOCKS * 256;
    for (; i < 2 * n4; i += stride){
      const int j = (i < n4) ? i : i - n4;
      const float4 v = (i < n4) ? ((const float4*)w1)[j] : ((const float4*)w2)[j];
      ushort4 o; o.x = f2bf(v.x); o.y = f2bf(v.y); o.z = f2bf(v.z); o.w = f2bf(v.w);
      if (i < n4) ((ushort4*)w1b)[j] = o; else ((ushort4*)w2b)[j] = o;
    }
    return;
  }
  // ---- RMSNorm + router part (no global atomics) ----
  const int t = blockIdx.x;
  const float4 xv = ((const float4*)(x + (size_t)t * DD))[tid];
  float ss = xv.x*xv.x + xv.y*xv.y + xv.z*xv.z + xv.w*xv.w;
  #pragma unroll
  for (int o = 32; o > 0; o >>= 1) ss += __shfl_down(ss, o);
  __shared__ float s_ss[4];
  __shared__ float s_p[4][8];
  if ((tid & 63) == 0) s_ss[tid >> 6] = ss;
  __syncthreads();
  const float tot = s_ss[0] + s_ss[1] + s_ss[2] + s_ss[3];
  const float inv = rsqrtf(tot * (1.0f / DD) + 1.1920929e-7f);
  const float4 nv = ((const float4*)nw)[tid];
  float4 xnv;
  xnv.x = xv.x*inv*nv.x; xnv.y = xv.y*inv*nv.y;
  xnv.z = xv.z*inv*nv.z; xnv.w = xv.w*inv*nv.w;
  ushort4 bv; bv.x = f2bf(xnv.x); bv.y = f2bf(xnv.y); bv.z = f2bf(xnv.z); bv.w = f2bf(xnv.w);
  ((ushort4*)(xn + (size_t)t * DD))[tid] = bv;
  float p[8];
  #pragma unroll
  for (int e = 0; e < 8; e++){
    const float4 g = ((const float4*)(gw + e * DD))[tid];
    p[e] = xnv.x*g.x + xnv.y*g.y + xnv.z*g.z + xnv.w*g.w;
  }
  #pragma unroll
  for (int e = 0; e < 8; e++){
    #pragma unroll
    for (int o = 32; o > 0; o >>= 1) p[e] += __shfl_down(p[e], o);
  }
  if ((tid & 63) == 0){
    #pragma unroll
    for (int e = 0; e < 8; e++) s_p[tid >> 6][e] = p[e];
  }
  __syncthreads();
  if (tid == 0){
    float lg[8], pr[8];
    #pragma unroll
    for (int e = 0; e < 8; e++) lg[e] = s_p[0][e] + s_p[1][e] + s_p[2][e] + s_p[3][e];
    float mx = lg[0];
    for (int e = 1; e < 8; e++) mx = fmaxf(mx, lg[e]);
    float sum = 0.f;
    for (int e = 0; e < 8; e++){ pr[e] = __expf(lg[e] - mx); sum += pr[e]; }
    const float is = 1.f / sum;
    for (int e = 0; e < 8; e++) pr[e] *= is;
    #pragma unroll
    for (int e = 0; e < 8; e++) probbuf[t * 8 + e] = pr[e];
    int e1 = 0;
    for (int e = 1; e < 8; e++) if (pr[e] > pr[e1]) e1 = e;       // first max (tie: lower idx)
    int e2 = (e1 == 0) ? 1 : 0;
    for (int e = 0; e < 8; e++) if (e != e1 && e != e2 && pr[e] > pr[e2]) e2 = e;
    const float wsum = fmaxf(pr[e1] + pr[e2], 1e-6f);
    topk_id[2*t] = e1; topk_id[2*t+1] = e2;
    topk_w[2*t] = pr[e1] / wsum; topk_w[2*t+1] = pr[e2] / wsum;
  }
}

// ------- single-block: counts, bases, lb loss, deterministic slot assignment ----
__global__ __launch_bounds__(256) void k_stats(
    const int* __restrict__ topk_id, const float* __restrict__ topk_w,
    const float* __restrict__ probbuf,
    int* __restrict__ counts, int* __restrict__ bases,
    int* __restrict__ slots_of, int* __restrict__ tok_of,
    float* __restrict__ slot_w,
    float* __restrict__ lb_out)
{
  const int tid = threadIdx.x;
  __shared__ int s_scan[256][8];
  __shared__ int s_base[8];

  int ids[16];
  int lc[8] = {}, lc1[8] = {};
  float lsp[8] = {};
  #pragma unroll
  for (int j = 0; j < 8; j++){
    const int t = tid * 8 + j;
    const int e1 = topk_id[2*t], e2 = topk_id[2*t+1];
    ids[2*j] = e1; ids[2*j+1] = e2;
    lc[e1]++; lc[e2]++; lc1[e1]++;
    const float4 p0 = ((const float4*)(probbuf + t * 8))[0];
    const float4 p1 = ((const float4*)(probbuf + t * 8))[1];
    lsp[0] += p0.x; lsp[1] += p0.y; lsp[2] += p0.z; lsp[3] += p0.w;
    lsp[4] += p1.x; lsp[5] += p1.y; lsp[6] += p1.z; lsp[7] += p1.w;
  }
  #pragma unroll
  for (int e = 0; e < 8; e++) s_scan[tid][e] = lc[e];
  __syncthreads();
  for (int off = 1; off < 256; off <<= 1){
    int v[8];
    if (tid >= off){
      #pragma unroll
      for (int e = 0; e < 8; e++) v[e] = s_scan[tid - off][e];
    }
    __syncthreads();
    if (tid >= off){
      #pragma unroll
      for (int e = 0; e < 8; e++) s_scan[tid][e] += v[e];
    }
    __syncthreads();
  }
  int   rc1[8]; float rsp[8];
  #pragma unroll
  for (int e = 0; e < 8; e++){ rc1[e] = lc1[e]; rsp[e] = lsp[e]; }
  #pragma unroll
  for (int e = 0; e < 8; e++){
    #pragma unroll
    for (int o = 32; o > 0; o >>= 1){
      rc1[e] += __shfl_down(rc1[e], o);
      rsp[e] += __shfl_down(rsp[e], o);
    }
  }
  __shared__ int   s_c1[4][8];
  __shared__ float s_sp[4][8];
  if ((tid & 63) == 0){
    const int w = tid >> 6;
    #pragma unroll
    for (int e = 0; e < 8; e++){ s_c1[w][e] = rc1[e]; s_sp[w][e] = rsp[e]; }
  }
  __syncthreads();
  if (tid == 0){
    int b = 0; float lb = 0.f;
    for (int e = 0; e < 8; e++){
      const int tot = s_scan[255][e];
      counts[e] = tot; bases[e] = b; s_base[e] = b; b += tot;
      const int   c1 = s_c1[0][e] + s_c1[1][e] + s_c1[2][e] + s_c1[3][e];
      const float sp = s_sp[0][e] + s_sp[1][e] + s_sp[2][e] + s_sp[3][e];
      lb += (float)c1 * sp;
    }
    lb_out[0] = 8.f * lb * (1.f / ((float)T_TOK * (float)T_TOK));
  }
  __syncthreads();
  int rank[8];
  #pragma unroll
  for (int e = 0; e < 8; e++) rank[e] = s_scan[tid][e] - lc[e];   // exclusive prefix
  #pragma unroll
  for (int j = 0; j < 8; j++){
    const int t = tid * 8 + j;
    #pragma unroll
    for (int k = 0; k < 2; k++){
      const int e = ids[2*j + k];
      const int slot = s_base[e] + rank[e]++;
      slots_of[2*t + k] = slot;
      tok_of[slot] = t;
      slot_w[slot] = topk_w[2*t + k];
    }
  }
}

// -------- grouped bf16 GEMM, B^T layout, 128x128 tile, BK=32 ---------------------
// XCD-aware: expert = blockIdx & 7 -> all of one expert's blocks land on one XCD,
// so its A-tiles + weights live in that XCD's 4 MiB L2 (cuts cross-XCD refetch).
// LDS chunk swizzle pos = (q + (row>>1)) & 3 breaks the 8-way bank conflict on
// fragment ds_read_b128 (row stride 64B) down to free 2-way.
// MODE 0 (+indirect A): C = silu(xn[tok_of[slot]] @ B^T) -> bf16 Hg
// MODE 1 (direct A):    C = (A @ B^T) * slot_w[row] -> fp32 Og
template<int KDIM, int NDIM, int MODE>
__global__ __launch_bounds__(256) void k_gemm(
    const unsigned short* __restrict__ Ag,
    const unsigned short* __restrict__ Bw,
    const int* __restrict__ counts, const int* __restrict__ bases,
    const int* __restrict__ tok_of,
    const float* __restrict__ slot_w,
    void* __restrict__ Cout)
{
  constexpr int NT = NDIM / 128;
  const int e  = blockIdx.x & 7;
  const int g  = blockIdx.x >> 3;
  const int mt = g / NT;
  const int nt = g - mt * NT;
  const int M = counts[e];
  if (mt * 128 >= M) return;
  const int sbase = bases[e];

  __shared__ __align__(16) unsigned short As[128 * 32];
  __shared__ __align__(16) unsigned short Bs[128 * 32];

  const int tid = threadIdx.x;
  const int l = tid & 63;
  const int w = tid >> 6;
  const int wm = (w >> 1) * 64, wn = (w & 1) * 64;
  const int lrow = l & 15, lq = l >> 4;          // k-quad 0..3 (8 elems each)

  // A row sources (hoisted out of K-loop): 2 staged rows per thread
  const unsigned short* arow[2];
  int kcs[2];
  #pragma unroll
  for (int i = 0; i < 2; i++){
    const int c = tid + i * 256;
    const int row = c >> 2, q = c & 3;
    kcs[i] = ((q - (row >> 1)) & 3) * 8;         // swizzled source k-chunk
    if (MODE == 0){
      const int slot = min(sbase + mt * 128 + row, NSLOT - 1);
      arow[i] = Ag + (size_t)tok_of[slot] * KDIM;
    } else {
      arow[i] = Ag + (size_t)(sbase + mt * 128 + row) * KDIM;
    }
  }
  const unsigned short* B0 = Bw + (size_t)e * NDIM * KDIM + (size_t)(nt * 128) * KDIM;

  floatx4 acc[4][4] = {};

  for (int k0 = 0; k0 < KDIM; k0 += 32){
    #pragma unroll
    for (int i = 0; i < 2; i++){
      const int c = tid + i * 256;
      const int row = c >> 2;
      const unsigned short* ga = arow[i] + k0 + kcs[i];
      const unsigned short* gb = B0 + (size_t)row * KDIM + k0 + kcs[i];
      __builtin_amdgcn_global_load_lds(
          (__attribute__((address_space(1))) unsigned int*)ga,
          (__attribute__((address_space(3))) unsigned int*)(As + c * 8), 16, 0, 0);
      __builtin_amdgcn_global_load_lds(
          (__attribute__((address_space(1))) unsigned int*)gb,
          (__attribute__((address_space(3))) unsigned int*)(Bs + c * 8), 16, 0, 0);
    }
    __syncthreads();
    bf16x8 af[4], bfv[4];
    #pragma unroll
    for (int mi = 0; mi < 4; mi++){
      const int row = wm + mi * 16 + lrow;
      const int p = (lq + (row >> 1)) & 3;
      af[mi] = *(const bf16x8*)(As + row * 32 + p * 8);
    }
    #pragma unroll
    for (int ni = 0; ni < 4; ni++){
      const int row = wn + ni * 16 + lrow;
      const int p = (lq + (row >> 1)) & 3;
      bfv[ni] = *(const bf16x8*)(Bs + row * 32 + p * 8);
    }
    #pragma unroll
    for (int mi = 0; mi < 4; mi++)
      #pragma unroll
      for (int ni = 0; ni < 4; ni++)
        acc[mi][ni] = __builtin_amdgcn_mfma_f32_16x16x32_bf16(af[mi], bfv[ni], acc[mi][ni], 0, 0, 0);
    __syncthreads();
  }

  // epilogue: C/D layout col = lane&15, row = (lane>>4)*4 + r
  const int rb = lq * 4;
  #pragma unroll
  for (int mi = 0; mi < 4; mi++){
    #pragma unroll
    for (int r = 0; r < 4; r++){
      const int row = mt * 128 + wm + mi * 16 + rb + r;
      if (row < M){
        #pragma unroll
        for (int ni = 0; ni < 4; ni++){
          const int col = nt * 128 + wn + ni * 16 + (l & 15);
          const float v = acc[mi][ni][r];
          if (MODE == 0){
            const float s = v / (1.f + __expf(-v));   // silu
            ((unsigned short*)Cout)[(size_t)(sbase + row) * NDIM + col] = f2bf(s);
          } else {
            const float wgt = slot_w[sbase + row];
            ((float*)Cout)[(size_t)(sbase + row) * NDIM + col] = v * wgt;
          }
        }
      }
    }
  }
}

// ---------------- residual combine ----------------
__global__ __launch_bounds__(256) void k_combine(
    const float* __restrict__ x, const float* __restrict__ Og,
    const int* __restrict__ slots_of, const float* __restrict__ scale,
    float* __restrict__ out)
{
  const int i = blockIdx.x * 256 + threadIdx.x;   // over T*D/4
  const int t = i >> 8;
  const int j = i & 255;
  const int s0 = slots_of[2*t], s1 = slots_of[2*t+1];
  const float4 a = ((const float4*)(Og + (size_t)s0 * DD))[j];
  const float4 b = ((const float4*)(Og + (size_t)s1 * DD))[j];
  const float4 xv = ((const float4*)x)[i];
  const float sc = 1.f / (1.f + __expf(-scale[0]));
  float4 o;
  o.x = xv.x + sc * (a.x + b.x);
  o.y = xv.y + sc * (a.y + b.y);
  o.z = xv.z + sc * (a.z + b.z);
  o.w = xv.w + sc * (a.w + b.w);
  ((float4*)out)[i] = o;
}

extern "C" void kernel_launch(void* const* d_in, const int* in_sizes, int n_in,
                              void* d_out, int out_size, void* d_ws, size_t ws_size,
                              hipStream_t stream)
{
  const float* x     = (const float*)d_in[0];   // [2,1024,1024]
  const float* gw    = (const float*)d_in[1];   // [8,1024]
  const float* w1    = (const float*)d_in[2];   // [8,2048,1024]
  const float* w2    = (const float*)d_in[3];   // [8,1024,2048]
  const float* nw    = (const float*)d_in[4];   // [1024]
  const float* scale = (const float*)d_in[5];   // [1]
  float* out = (float*)d_out;                   // 2097152 + 1 (lb loss)

  char* ws = (char*)d_ws;
  int*   counts  = (int*)(ws + 0);
  int*   bases   = (int*)(ws + 64);
  int*   topk_id = (int*)(ws + 1024);            // 16 KB
  float* topk_w  = (float*)(ws + 20480);         // 16 KB
  int*   slots_of= (int*)(ws + 40960);           // 16 KB
  float* slot_w  = (float*)(ws + 61440);         // 16 KB (SLOTPAD floats fits)
  int*   tok_of  = (int*)(ws + 81920);           // 16 KB
  float* probbuf = (float*)(ws + 102400);        // 64 KB
  unsigned short* xn  = (unsigned short*)(ws + 262144);
  unsigned short* Hg  = xn + (size_t)T_TOK * DD;
  float*          Og  = (float*)(Hg + (size_t)SLOTPAD * FF);
  unsigned short* w1b = (unsigned short*)(Og + (size_t)SLOTPAD * DD);
  unsigned short* w2b = w1b + (size_t)EE * FF * DD;

  k_front<<<T_TOK + CVT_BLOCKS, 256, 0, stream>>>(x, gw, nw, w1, w2, xn,
                                                  topk_id, topk_w, probbuf, w1b, w2b);
  k_stats<<<1, 256, 0, stream>>>(topk_id, topk_w, probbuf, counts, bases,
                                 slots_of, tok_of, slot_w, out + (size_t)T_TOK * DD);
  k_gemm<1024, 2048, 0><<<EE * 16 * (FF/128), 256, 0, stream>>>(xn, w1b, counts, bases, tok_of, nullptr, Hg);
  k_gemm<2048, 1024, 1><<<EE * 16 * (DD/128), 256, 0, stream>>>(Hg, w2b, counts, bases, nullptr, slot_w, Og);
  k_combine<<<T_TOK * DD / 4 / 256, 256, 0, stream>>>(x, Og, slots_of, scale, out);
}